// Round 8
// baseline (523.891 us; speedup 1.0000x reference)
//
#include <hip/hip_runtime.h>
#include <math.h>

#define TT 16
#define BB 32
#define NN 256
#define DD 128
#define NSTEPS 5
#define SKIPF 0.3f
#define EPSF 1e-8f

// R7: only outs[-1] is live -> GRU for t<15 is dead code.
// R9: V eliminated; gram computed from staged low-precision x.
// R10: register-resident gram2. R11: LDS tables (issue-saturated at 91%).
// R12: f16 packed-math gram (VALU 62 + MFMA 41 = 103% -> pure inst-count).
// R15: 64x64 gram tiles: gram2 145us (issue-bound at 94%).
// R16: k_prep (MFMA norms + f16 convert): 363.6us. gram2 144us unchanged.
// R17 (this round): fuse hTinit + 5x k_step + k_fc into ONE k_gru.
//   ~219us of non-gram2 time >> ~70us of modeled kernel time -> the excess
//   lives in 12 serialized dispatches (launch gaps + latency-bound steps at
//   1 block/CU). k_gru: grid 256 (8 rg x 32 b, all co-resident), 5 steps
//   in-kernel with device-scope 8-block barriers per batch; x15-transpose
//   as prologue; fc accumulated IN-REGISTER during step 4 (no final hT
//   write, no fc re-read). Step-body indexing verbatim from verified k_step.

typedef __attribute__((ext_vector_type(8))) short bf16x8;
typedef __attribute__((ext_vector_type(4))) float f32x4;
typedef __attribute__((ext_vector_type(8))) _Float16 half8;
typedef __attribute__((ext_vector_type(2))) _Float16 h2;

__device__ __forceinline__ unsigned short f2bf(float f) {
    union { float f; unsigned u; } v; v.f = f;
    unsigned r = (v.u + 0x7FFF + ((v.u >> 16) & 1)) >> 16;
    return (unsigned short)r;
}
__device__ __forceinline__ float bf2f(unsigned short u) {
    union { unsigned u; float f; } v; v.u = ((unsigned)u) << 16; return v.f;
}
__device__ __forceinline__ unsigned pack2(unsigned short a, unsigned short b) {
    return (unsigned)a | ((unsigned)b << 16);
}
// packed f32->f16 convert (RTZ), 1 inst for 2 elems
__device__ __forceinline__ unsigned pkrtz(float a, float b) {
    unsigned r;
    asm("v_cvt_pkrtz_f16_f32 %0, %1, %2" : "=v"(r) : "v"(a), "v"(b));
    return r;
}
__device__ __forceinline__ h2 u2h(unsigned u) {
    union { unsigned u; h2 h; } v; v.u = u; return v.h;
}
__device__ __forceinline__ float sigmoidf_(float x) {
    return 1.0f / (1.0f + __expf(-x));
}
__device__ __forceinline__ float tanhf_(float x) {
    return 1.0f - 2.0f / (__expf(2.0f * x) + 1.0f);
}

// device-scope barrier among the 8 rg-blocks of one batch.
// Requires all participating blocks resident (grid 256 <= 256 CUs, small
// footprint -> guaranteed). Counter zeroed host-side per launch.
__device__ __forceinline__ void bbar(int* c) {
    __syncthreads();
    __threadfence();                      // make this block's writes device-visible
    if (threadIdx.x == 0) {
        __hip_atomic_fetch_add(c, 1, __ATOMIC_RELEASE, __HIP_MEMORY_SCOPE_AGENT);
        while (__hip_atomic_load(c, __ATOMIC_ACQUIRE, __HIP_MEMORY_SCOPE_AGENT) < 8)
            __builtin_amdgcn_s_sleep(2);
    }
    __syncthreads();
    // per-thread acquire so every thread's subsequent reads see remote writes
    (void)__hip_atomic_load(c, __ATOMIC_ACQUIRE, __HIP_MEMORY_SCOPE_AGENT);
}

// ---------------------------------------------------------------------------
// prep: per tb block (512 blocks, 256 thr):
//   xh = f16(x)  (32 MB total, coalesced)
//   invnH[tb][h][n] = dup-f16(1/(sqrt(sum_d x^2 w^2)+eps)) via MFMA:
//     A = x^2 (f16, LDS, XOR-16 swizzle), B = w^2 (f16, from L1/global).
// ---------------------------------------------------------------------------
__global__ __launch_bounds__(256) void k_prep(const float* __restrict__ x,
                                              const unsigned* __restrict__ wsqH,
                                              unsigned short* __restrict__ xh,
                                              unsigned* __restrict__ invnH) {
    int tb = blockIdx.x;
    int tid = threadIdx.x;
    int wave = tid >> 6, lane = tid & 63;
    int m16 = lane & 15, quad = lane >> 4;

    __shared__ unsigned short xsq[256 * 128];   // 64 KB f16, XOR-16 by row&7

    const float* xb = x + ((size_t)tb << 15);
    unsigned short* xhb = xh + ((size_t)tb << 15);

    #pragma unroll
    for (int it = 0; it < 16; ++it) {
        int flat = (it << 11) + (tid << 3);
        float4 a = *(const float4*)(xb + flat);
        float4 b = *(const float4*)(xb + flat + 4);
        uint4 o;
        o.x = pkrtz(a.x, a.y); o.y = pkrtz(a.z, a.w);
        o.z = pkrtz(b.x, b.y); o.w = pkrtz(b.z, b.w);
        *(uint4*)(xhb + flat) = o;
        uint4 q;
        q.x = pkrtz(a.x * a.x, a.y * a.y); q.y = pkrtz(a.z * a.z, a.w * a.w);
        q.z = pkrtz(b.x * b.x, b.y * b.y); q.w = pkrtz(b.z * b.z, b.w * b.w);
        int row = flat >> 7;
        int byteoff = (flat << 1) ^ ((row & 7) << 4);
        *(uint4*)((char*)xsq + byteoff) = q;
    }
    __syncthreads();

    half8 wf[4];
    #pragma unroll
    for (int ks = 0; ks < 4; ++ks)
        wf[ks] = *(const half8*)((const unsigned short*)wsqH + (m16 << 7) + (ks << 5) + (quad << 3));

    #pragma unroll
    for (int sub = 0; sub < 4; ++sub) {
        int rbase = (wave << 6) + (sub << 4);
        f32x4 acc = (f32x4){0.f, 0.f, 0.f, 0.f};
        #pragma unroll
        for (int ks = 0; ks < 4; ++ks) {
            int row = rbase + m16;
            int byteoff = ((row << 8) + (ks << 6) + (quad << 4)) ^ ((row & 7) << 4);
            half8 af = *(const half8*)((const char*)xsq + byteoff);
            acc = __builtin_amdgcn_mfma_f32_16x16x32_f16(af, wf[ks], acc, 0, 0, 0);
        }
        unsigned out[4];
        #pragma unroll
        for (int r = 0; r < 4; ++r) {
            float inv = 1.0f / (sqrtf(acc[r]) + EPSF);
            out[r] = pkrtz(inv, inv);
        }
        int n = rbase + (quad << 2);
        *(uint4*)(invnH + ((size_t)tb << 12) + (m16 << 8) + n) = *(uint4*)out;
    }
}

// ---------------------------------------------------------------------------
// gram2 (f16 packed, 64x64 wave tiles) — VERIFIED R15/R16.
// grid = 4 rg x 512 tb = 2048 blocks, 256 threads, LDS 21 KB.
// ---------------------------------------------------------------------------
__global__ __launch_bounds__(256, 2) void k_gram2(const unsigned short* __restrict__ xhp,
                                                  const unsigned* __restrict__ wsqH,
                                                  const unsigned* __restrict__ invnH,
                                                  unsigned short* __restrict__ attn) {
    int bid = blockIdx.x;
    int tb = bid & 511;
    int rg = bid >> 9;                  // 0..3
    int n0 = rg << 6;
    int tid = threadIdx.x;
    int wave = tid >> 6, lane = tid & 63;
    int m16 = lane & 15, quad = lane >> 4;
    int wcol = wave << 6;

    __shared__ unsigned wS[16 * 64];     // 4 KB
    __shared__ unsigned ivS[16 * 256];   // 16 KB
    __shared__ float rsum[4][64];        // 1 KB

    const unsigned short* Xb = xhp + ((size_t)tb << 15);

    {
        uint4 v = *(const uint4*)(wsqH + (tid << 2));
        *(uint4*)(wS + (tid << 2)) = v;
    }
    {
        const unsigned* src = invnH + ((size_t)tb << 12);
        #pragma unroll
        for (int hh = 0; hh < 16; ++hh)
            ivS[(hh << 8) + tid] = src[(hh << 8) + tid];
    }

    half8 Bf[4][4];
    #pragma unroll
    for (int ks = 0; ks < 4; ++ks)
        #pragma unroll
        for (int cb = 0; cb < 4; ++cb)
            Bf[ks][cb] = *(const half8*)(Xb + ((wcol + (cb << 4) + m16) << 7) + (ks << 5) + (quad << 3));

    half8 Af[4][4];
    #pragma unroll
    for (int rb = 0; rb < 4; ++rb)
        #pragma unroll
        for (int ks = 0; ks < 4; ++ks)
            Af[rb][ks] = *(const half8*)(Xb + ((n0 + (rb << 4) + m16) << 7) + (ks << 5) + (quad << 3));

    f32x4 att[4][4];
    #pragma unroll
    for (int rb = 0; rb < 4; ++rb)
        #pragma unroll
        for (int cb = 0; cb < 4; ++cb) att[rb][cb] = (f32x4){0.f, 0.f, 0.f, 0.f};

    __syncthreads();

    union H8 { half8 v; h2 p[4]; };

    #pragma unroll 1
    for (int h = 0; h < 16; ++h) {
        const unsigned* ivh = ivS + (h << 8);
        h2 ivr[4], ivc[4];
        #pragma unroll
        for (int rb = 0; rb < 4; ++rb) ivr[rb] = u2h(ivh[n0 + (rb << 4) + m16]);
        #pragma unroll
        for (int cb = 0; cb < 4; ++cb) ivc[cb] = u2h(ivh[wcol + (cb << 4) + m16]);

        #pragma unroll
        for (int ks = 0; ks < 4; ++ks) {
            uint4 wu = *(const uint4*)(wS + (h << 6) + (ks << 4) + (quad << 2));
            h2 w0 = u2h(wu.x), w1 = u2h(wu.y), w2 = u2h(wu.z), w3 = u2h(wu.w);

            H8 afr[4];
            #pragma unroll
            for (int rb = 0; rb < 4; ++rb) {
                H8 a; a.v = Af[rb][ks];
                h2 s = ivr[rb];
                afr[rb].p[0] = a.p[0] * (w0 * s);
                afr[rb].p[1] = a.p[1] * (w1 * s);
                afr[rb].p[2] = a.p[2] * (w2 * s);
                afr[rb].p[3] = a.p[3] * (w3 * s);
            }
            #pragma unroll
            for (int cb = 0; cb < 4; ++cb) {
                H8 b; b.v = Bf[ks][cb];
                H8 bf;
                bf.p[0] = b.p[0] * ivc[cb];
                bf.p[1] = b.p[1] * ivc[cb];
                bf.p[2] = b.p[2] * ivc[cb];
                bf.p[3] = b.p[3] * ivc[cb];
                #pragma unroll
                for (int rb = 0; rb < 4; ++rb)
                    att[rb][cb] = __builtin_amdgcn_mfma_f32_16x16x32_f16(afr[rb].v, bf.v, att[rb][cb], 0, 0, 0);
            }
        }
    }

    float rs[4][4];
    #pragma unroll
    for (int rb = 0; rb < 4; ++rb)
        #pragma unroll
        for (int r = 0; r < 4; ++r) {
            float s = 0.f;
            #pragma unroll
            for (int cb = 0; cb < 4; ++cb) {
                float v = fmaxf(att[rb][cb][r], 0.0f);
                att[rb][cb][r] = v;
                s += v;
            }
            rs[rb][r] = s;
        }
    #pragma unroll
    for (int m = 1; m < 16; m <<= 1)
        #pragma unroll
        for (int rb = 0; rb < 4; ++rb)
            #pragma unroll
            for (int r = 0; r < 4; ++r)
                rs[rb][r] += __shfl_xor(rs[rb][r], m, 64);
    if (m16 == 0) {
        #pragma unroll
        for (int rb = 0; rb < 4; ++rb)
            #pragma unroll
            for (int r = 0; r < 4; ++r)
                rsum[wave][(rb << 4) + (quad << 2) + r] = rs[rb][r];
    }
    __syncthreads();

    unsigned short* outb = attn + ((size_t)tb << 16);
    #pragma unroll
    for (int rb = 0; rb < 4; ++rb) {
        #pragma unroll
        for (int r = 0; r < 4; ++r) {
            int row = (rb << 4) + (quad << 2) + r;
            float tot = rsum[0][row] + rsum[1][row] + rsum[2][row] + rsum[3][row];
            float inv = (1.0f - SKIPF) / (tot + 16.0f * EPSF);
            #pragma unroll
            for (int cb = 0; cb < 4; ++cb) {
                int col = wcol + (cb << 4) + m16;
                outb[((size_t)(n0 + row) << 8) + col] = f2bf(att[rb][cb][r] * inv);
            }
        }
    }
}

// ---------------------------------------------------------------------------
// scanlast: a=supports; a=0.3a+attn_t; write only A_15 (bf16). grid 2048x256.
// ---------------------------------------------------------------------------
__global__ __launch_bounds__(256) void k_scanlast(const float* __restrict__ supports,
                                                  const unsigned short* __restrict__ AttA,
                                                  unsigned short* __restrict__ Afin) {
    size_t flat = ((size_t)blockIdx.x * 256 + threadIdx.x) * 4;
    float4 s4 = *(const float4*)(supports + flat);
    float a0 = s4.x, a1 = s4.y, a2 = s4.z, a3 = s4.w;
    #pragma unroll
    for (int t = 0; t < TT; ++t) {
        const unsigned short* p = AttA + ((size_t)t << 21) + flat;
        uint2 u = *(const uint2*)p;
        a0 = SKIPF * a0 + bf2f((unsigned short)(u.x & 0xffff));
        a1 = SKIPF * a1 + bf2f((unsigned short)(u.x >> 16));
        a2 = SKIPF * a2 + bf2f((unsigned short)(u.y & 0xffff));
        a3 = SKIPF * a3 + bf2f((unsigned short)(u.y >> 16));
    }
    uint2 o;
    o.x = pack2(f2bf(a0), f2bf(a1));
    o.y = pack2(f2bf(a2), f2bf(a3));
    *(uint2*)(Afin + flat) = o;
}

// ---------------------------------------------------------------------------
// wprep: bf16-transposed weights WT[dout][k] + packed-f16 w^2 table
// ---------------------------------------------------------------------------
__global__ __launch_bounds__(256) void k_wprep(const float* __restrict__ Wa,
                                               const float* __restrict__ Wr,
                                               const float* __restrict__ Wz,
                                               const float* __restrict__ Wh,
                                               const float* __restrict__ Wgl,
                                               unsigned short* __restrict__ WaT,
                                               unsigned short* __restrict__ WrT,
                                               unsigned short* __restrict__ WzT,
                                               unsigned short* __restrict__ WhT,
                                               unsigned* __restrict__ wsqH) {
    int idx = blockIdx.x * 256 + threadIdx.x;     // 0..32767
    if (idx < 16384) {
        int dout = idx >> 7, din = idx & 127;
        WaT[idx] = f2bf(Wa[(din << 7) + dout]);
    }
    if (idx < 1024) {
        int h = idx >> 6, j = idx & 63;
        float w0 = Wgl[(h << 7) + (j << 1)];
        float w1 = Wgl[(h << 7) + (j << 1) + 1];
        wsqH[idx] = pkrtz(w0 * w0, w1 * w1);
    }
    {
        int dout = idx >> 8, dk = idx & 255;
        WrT[idx] = f2bf(Wr[(dk << 7) + dout]);
        WzT[idx] = f2bf(Wz[(dk << 7) + dout]);
        WhT[idx] = f2bf(Wh[(dk << 7) + dout]);
    }
}

// ---------------------------------------------------------------------------
// gru: FUSED hTinit + 5x GRU step + fc. grid = 8 rg x 32 b = 256 blocks,
// 256 threads, all co-resident. Cross-block dependency (bmm needs full h)
// handled by device-scope 8-block barrier per batch. Step body is the
// verified k_step verbatim. fc accumulated in-register in step 4.
// ---------------------------------------------------------------------------
__global__ __launch_bounds__(256) void k_gru(
    const float* __restrict__ x15,
    const unsigned short* __restrict__ Afin,
    const unsigned short* __restrict__ WaT, const float* __restrict__ ba,
    const unsigned short* __restrict__ WrT, const float* __restrict__ br,
    const unsigned short* __restrict__ WzT, const float* __restrict__ bz,
    const unsigned short* __restrict__ WhT, const float* __restrict__ bh,
    const float* __restrict__ Wfc, const float* __restrict__ bfc,
    unsigned short* __restrict__ hTa, unsigned short* __restrict__ hTbuf,
    int* __restrict__ cnt, float* __restrict__ out) {

    int bid = blockIdx.x;
    int b = bid & 31, rg = bid >> 5;
    int n0 = rg << 5;
    int tid = threadIdx.x;
    int wave = tid >> 6, lane = tid & 63;
    int m16 = lane & 15, quad = lane >> 4;
    int wcol = wave << 5;

    __shared__ unsigned short msgS[32 * 136];
    __shared__ unsigned short ahS[32 * 264];   // k 0..127 = a, 128..255 = h (later r*h)
    __shared__ float rf0[4], rf1[4];

    int* cbp = cnt + b * 5;

    // ---- prologue: hTa[b][d][n0..n0+32) = bf16(x15[b][n][d]) (hTinit) ----
    {
        float* tl = (float*)ahS;            // 32x33 f32 = 4.2 KB inside ahS
        int i = tid >> 5, j = tid & 31;
        for (int dt = 0; dt < 4; ++dt) {
            int d0 = dt << 5;
            #pragma unroll
            for (int s4 = 0; s4 < 4; ++s4) {
                int nl = (s4 << 3) + i;
                tl[nl * 33 + j] = x15[((size_t)(b * 256 + n0 + nl) << 7) + d0 + j];
            }
            __syncthreads();
            #pragma unroll
            for (int s4 = 0; s4 < 4; ++s4) {
                int dd = (s4 << 3) + i;
                hTa[((size_t)(b * 128 + d0 + dd) << 8) + n0 + j] = f2bf(tl[j * 33 + dd]);
            }
            __syncthreads();
        }
    }
    bbar(cbp + 0);

    float fca = 0.f, fcb = 0.f;
    const unsigned short* Ab = Afin + ((size_t)b << 16) + ((size_t)n0 << 8);

    for (int s = 0; s < NSTEPS; ++s) {
        const unsigned short* hTin = (s & 1) ? hTbuf : hTa;
        unsigned short* hTo = (s & 1) ? hTa : hTbuf;
        const unsigned short* hTb = hTin + ((size_t)b << 15);

        // stage h-half of ahS (transpose: ahS[row][128+d] = hT[d][n0+row])
        #pragma unroll
        for (int j = 0; j < 16; ++j) {
            int idx = (j << 8) + tid;
            int d = idx >> 5, row = idx & 31;
            ahS[row * 264 + 128 + d] = hTb[((size_t)d << 8) + n0 + row];
        }

        // ---- bmm: msg = A_tile @ h  (K=256) ----
        f32x4 acc[2][2];
        #pragma unroll
        for (int rb = 0; rb < 2; ++rb)
            #pragma unroll
            for (int cb = 0; cb < 2; ++cb) acc[rb][cb] = (f32x4){0.f, 0.f, 0.f, 0.f};

        #pragma unroll 2
        for (int ks = 0; ks < 8; ++ks) {
            bf16x8 af[2], bf[2];
            #pragma unroll
            for (int rb = 0; rb < 2; ++rb)
                af[rb] = *(const bf16x8*)(Ab + (((rb << 4) + m16) << 8) + (ks << 5) + (quad << 3));
            #pragma unroll
            for (int cb = 0; cb < 2; ++cb)
                bf[cb] = *(const bf16x8*)(hTb + ((wcol + (cb << 4) + m16) << 8) + (ks << 5) + (quad << 3));
            #pragma unroll
            for (int rb = 0; rb < 2; ++rb)
                #pragma unroll
                for (int cb = 0; cb < 2; ++cb)
                    acc[rb][cb] = __builtin_amdgcn_mfma_f32_16x16x32_bf16(af[rb], bf[cb], acc[rb][cb], 0, 0, 0);
        }
        #pragma unroll
        for (int rb = 0; rb < 2; ++rb)
            #pragma unroll
            for (int cb = 0; cb < 2; ++cb)
                #pragma unroll
                for (int r = 0; r < 4; ++r)
                    msgS[((rb << 4) + (quad << 2) + r) * 136 + wcol + (cb << 4) + m16] = f2bf(acc[rb][cb][r]);
        __syncthreads();   // covers h-half staging too

        // ---- a = msg @ Wa + ba ----
        #pragma unroll
        for (int rb = 0; rb < 2; ++rb)
            #pragma unroll
            for (int cb = 0; cb < 2; ++cb) acc[rb][cb] = (f32x4){0.f, 0.f, 0.f, 0.f};
        #pragma unroll
        for (int ks = 0; ks < 4; ++ks) {
            bf16x8 af[2], bf[2];
            #pragma unroll
            for (int rb = 0; rb < 2; ++rb)
                af[rb] = *(const bf16x8*)(msgS + ((rb << 4) + m16) * 136 + (ks << 5) + (quad << 3));
            #pragma unroll
            for (int cb = 0; cb < 2; ++cb)
                bf[cb] = *(const bf16x8*)(WaT + ((wcol + (cb << 4) + m16) << 7) + (ks << 5) + (quad << 3));
            #pragma unroll
            for (int rb = 0; rb < 2; ++rb)
                #pragma unroll
                for (int cb = 0; cb < 2; ++cb)
                    acc[rb][cb] = __builtin_amdgcn_mfma_f32_16x16x32_bf16(af[rb], bf[cb], acc[rb][cb], 0, 0, 0);
        }
        {
            float bav[2];
            #pragma unroll
            for (int cb = 0; cb < 2; ++cb) bav[cb] = ba[wcol + (cb << 4) + m16];
            #pragma unroll
            for (int rb = 0; rb < 2; ++rb)
                #pragma unroll
                for (int cb = 0; cb < 2; ++cb)
                    #pragma unroll
                    for (int r = 0; r < 4; ++r)
                        ahS[((rb << 4) + (quad << 2) + r) * 264 + wcol + (cb << 4) + m16] =
                            f2bf(acc[rb][cb][r] + bav[cb]);
        }
        __syncthreads();

        // h_old
        float hv[2][2][4];
        #pragma unroll
        for (int rb = 0; rb < 2; ++rb)
            #pragma unroll
            for (int cb = 0; cb < 2; ++cb) {
                int col = wcol + (cb << 4) + m16;
                uint2 u = *(const uint2*)(hTb + ((size_t)col << 8) + n0 + (rb << 4) + (quad << 2));
                hv[rb][cb][0] = bf2f((unsigned short)(u.x & 0xffff));
                hv[rb][cb][1] = bf2f((unsigned short)(u.x >> 16));
                hv[rb][cb][2] = bf2f((unsigned short)(u.y & 0xffff));
                hv[rb][cb][3] = bf2f((unsigned short)(u.y >> 16));
            }

        // ---- r and z ----
        f32x4 racc[2][2], zacc[2][2];
        #pragma unroll
        for (int rb = 0; rb < 2; ++rb)
            #pragma unroll
            for (int cb = 0; cb < 2; ++cb) {
                racc[rb][cb] = (f32x4){0.f, 0.f, 0.f, 0.f};
                zacc[rb][cb] = (f32x4){0.f, 0.f, 0.f, 0.f};
            }
        #pragma unroll 2
        for (int ks = 0; ks < 8; ++ks) {
            bf16x8 af[2], bfr[2], bfz[2];
            #pragma unroll
            for (int rb = 0; rb < 2; ++rb)
                af[rb] = *(const bf16x8*)(ahS + ((rb << 4) + m16) * 264 + (ks << 5) + (quad << 3));
            #pragma unroll
            for (int cb = 0; cb < 2; ++cb) {
                int dout = wcol + (cb << 4) + m16;
                bfr[cb] = *(const bf16x8*)(WrT + (dout << 8) + (ks << 5) + (quad << 3));
                bfz[cb] = *(const bf16x8*)(WzT + (dout << 8) + (ks << 5) + (quad << 3));
            }
            #pragma unroll
            for (int rb = 0; rb < 2; ++rb)
                #pragma unroll
                for (int cb = 0; cb < 2; ++cb) {
                    racc[rb][cb] = __builtin_amdgcn_mfma_f32_16x16x32_bf16(af[rb], bfr[cb], racc[rb][cb], 0, 0, 0);
                    zacc[rb][cb] = __builtin_amdgcn_mfma_f32_16x16x32_bf16(af[rb], bfz[cb], zacc[rb][cb], 0, 0, 0);
                }
        }
        float zv[2][2][4];
        {
            float brv[2], bzv[2];
            #pragma unroll
            for (int cb = 0; cb < 2; ++cb) {
                brv[cb] = br[wcol + (cb << 4) + m16];
                bzv[cb] = bz[wcol + (cb << 4) + m16];
            }
            #pragma unroll
            for (int rb = 0; rb < 2; ++rb)
                #pragma unroll
                for (int cb = 0; cb < 2; ++cb)
                    #pragma unroll
                    for (int r = 0; r < 4; ++r) {
                        racc[rb][cb][r] = sigmoidf_(racc[rb][cb][r] + brv[cb]);
                        zv[rb][cb][r]  = sigmoidf_(zacc[rb][cb][r] + bzv[cb]);
                    }
        }
        __syncthreads();   // all ahS reads done -> safe to overwrite h-half

        #pragma unroll
        for (int rb = 0; rb < 2; ++rb)
            #pragma unroll
            for (int cb = 0; cb < 2; ++cb)
                #pragma unroll
                for (int r = 0; r < 4; ++r)
                    ahS[((rb << 4) + (quad << 2) + r) * 264 + 128 + wcol + (cb << 4) + m16] =
                        f2bf(racc[rb][cb][r] * hv[rb][cb][r]);
        __syncthreads();

        // ---- h_tilde ----
        #pragma unroll
        for (int rb = 0; rb < 2; ++rb)
            #pragma unroll
            for (int cb = 0; cb < 2; ++cb) acc[rb][cb] = (f32x4){0.f, 0.f, 0.f, 0.f};
        #pragma unroll 2
        for (int ks = 0; ks < 8; ++ks) {
            bf16x8 af[2], bf[2];
            #pragma unroll
            for (int rb = 0; rb < 2; ++rb)
                af[rb] = *(const bf16x8*)(ahS + ((rb << 4) + m16) * 264 + (ks << 5) + (quad << 3));
            #pragma unroll
            for (int cb = 0; cb < 2; ++cb)
                bf[cb] = *(const bf16x8*)(WhT + ((wcol + (cb << 4) + m16) << 8) + (ks << 5) + (quad << 3));
            #pragma unroll
            for (int rb = 0; rb < 2; ++rb)
                #pragma unroll
                for (int cb = 0; cb < 2; ++cb)
                    acc[rb][cb] = __builtin_amdgcn_mfma_f32_16x16x32_bf16(af[rb], bf[cb], acc[rb][cb], 0, 0, 0);
        }

        // ---- update: write hTo (s<4) or accumulate fc in-register (s==4) ----
        {
            float bhv[2];
            #pragma unroll
            for (int cb = 0; cb < 2; ++cb) bhv[cb] = bh[wcol + (cb << 4) + m16];
            #pragma unroll
            for (int rb = 0; rb < 2; ++rb)
                #pragma unroll
                for (int cb = 0; cb < 2; ++cb) {
                    int col = wcol + (cb << 4) + m16;
                    unsigned short pk[4];
                    #pragma unroll
                    for (int r = 0; r < 4; ++r) {
                        float ht = tanhf_(acc[rb][cb][r] + bhv[cb]);
                        float hn = hv[rb][cb][r] + zv[rb][cb][r] * (ht - hv[rb][cb][r]);
                        pk[r] = f2bf(hn);
                    }
                    if (s < NSTEPS - 1) {
                        uint2 p;
                        p.x = pack2(pk[0], pk[1]); p.y = pack2(pk[2], pk[3]);
                        *(uint2*)(hTo + ((size_t)(b * 128 + col) << 8) + n0 + (rb << 4) + (quad << 2)) = p;
                    } else {
                        #pragma unroll
                        for (int r = 0; r < 4; ++r) {
                            int nn = n0 + (rb << 4) + (quad << 2) + r;
                            float hval = bf2f(pk[r]);
                            const float2 w = *(const float2*)(Wfc + (size_t)(nn * 128 + col) * 2);
                            fca = fmaf(hval, w.x, fca);
                            fcb = fmaf(hval, w.y, fcb);
                        }
                    }
                }
        }
        if (s < NSTEPS - 1) bbar(cbp + 1 + s);
    }

    // ---- fc reduce: wave -> block -> atomicAdd ----
    #pragma unroll
    for (int off = 32; off; off >>= 1) {
        fca += __shfl_down(fca, off, 64);
        fcb += __shfl_down(fcb, off, 64);
    }
    if (lane == 0) { rf0[wave] = fca; rf1[wave] = fcb; }
    __syncthreads();
    if (tid == 0) {
        float s0 = rf0[0] + rf0[1] + rf0[2] + rf0[3];
        float s1 = rf1[0] + rf1[1] + rf1[2] + rf1[3];
        if (rg == 0) { s0 += bfc[0]; s1 += bfc[1]; }
        atomicAdd(&out[b * 2 + 0], s0);
        atomicAdd(&out[b * 2 + 1], s1);
    }
}

// ---------------------------------------------------------------------------
extern "C" void kernel_launch(void* const* d_in, const int* in_sizes, int n_in,
                              void* d_out, int out_size, void* d_ws, size_t ws_size,
                              hipStream_t stream) {
    const float* x_all    = (const float*)d_in[0];
    const float* supports = (const float*)d_in[1];
    const float* Wgl = (const float*)d_in[2];
    const float* Wa  = (const float*)d_in[3];
    const float* ba  = (const float*)d_in[4];
    const float* Wr  = (const float*)d_in[5];
    const float* br  = (const float*)d_in[6];
    const float* Wz  = (const float*)d_in[7];
    const float* bz  = (const float*)d_in[8];
    const float* Wh  = (const float*)d_in[9];
    const float* bh  = (const float*)d_in[10];
    const float* Wfc = (const float*)d_in[11];
    const float* bfc = (const float*)d_in[12];
    float* out = (float*)d_out;

    char* p = (char*)d_ws;
    auto alloc = [&](size_t bytes) { char* r = p; p += (bytes + 255) & ~(size_t)255; return r; };

    unsigned short* AttA = (unsigned short*)alloc((size_t)TT * BB * NN * NN * 2);  // 64 MB
    unsigned short* xh   = (unsigned short*)alloc((size_t)TT * BB * NN * DD * 2);  // 32 MB (f16)
    unsigned* invnH      = (unsigned*)alloc((size_t)TT * BB * 16 * NN * 4);        // 8 MB (dup f16)
    unsigned short* Afin = (unsigned short*)alloc((size_t)BB * NN * NN * 2);       // 4 MB
    unsigned short* hT0  = (unsigned short*)alloc((size_t)BB * DD * NN * 2);       // 2 MB
    unsigned short* hT1  = (unsigned short*)alloc((size_t)BB * DD * NN * 2);       // 2 MB
    unsigned short* WaT  = (unsigned short*)alloc(128 * 128 * 2);
    unsigned short* WrT  = (unsigned short*)alloc(256 * 128 * 2);
    unsigned short* WzT  = (unsigned short*)alloc(256 * 128 * 2);
    unsigned short* WhT  = (unsigned short*)alloc(256 * 128 * 2);
    unsigned* wsqH       = (unsigned*)alloc(16 * 64 * 4);                          // 4 KB
    int* cntB            = (int*)alloc(32 * 5 * 4);                                // 640 B
    // total ~112.5 MB

    // zero barrier counters + output (graph-replay safe: stream-ordered)
    hipMemsetAsync(cntB, 0, 32 * 5 * 4, stream);
    hipMemsetAsync(d_out, 0, (size_t)out_size * sizeof(float), stream);

    k_wprep<<<128, 256, 0, stream>>>(Wa, Wr, Wz, Wh, Wgl, WaT, WrT, WzT, WhT, wsqH);
    k_prep<<<TT * BB, 256, 0, stream>>>(x_all, wsqH, xh, invnH);

    // attention path: all 16 t in one dispatch
    k_gram2<<<4 * TT * BB, 256, 0, stream>>>(xh, wsqH, invnH, AttA);
    k_scanlast<<<2048, 256, 0, stream>>>(supports, AttA, Afin);

    // GRU path: ONLY t=15 is live; fully fused (hTinit + 5 steps + fc)
    const float* x15 = x_all + (size_t)15 * BB * NN * DD;
    k_gru<<<8 * BB, 256, 0, stream>>>(x15, Afin,
                                      WaT, ba, WrT, br, WzT, bz, WhT, bh,
                                      Wfc, bfc, hT0, hT1, cntB, out);
}

// Round 9
// 304.847 us; speedup vs baseline: 1.7185x; 1.7185x over previous
//
#include <hip/hip_runtime.h>
#include <math.h>

#define TT 16
#define BB 32
#define NN 256
#define DD 128
#define NSTEPS 5
#define SKIPF 0.3f
#define EPSF 1e-8f
// truncated scan: timesteps t < T0 contribute <= 0.3^(16-T0) ~ 2e-5 to A_15
// (attn rows are normalized) -- 400x below the 0.0078 tolerance. Skip them.
#define T0 7
#define TBLIVE ((TT - T0) * BB)    // 288 live (t,b) pairs

// R7: only outs[-1] is live -> GRU for t<15 is dead code.
// R9: V eliminated; gram computed from staged low-precision x.
// R10: register-resident gram2. R11: LDS tables (issue-saturated at 91%).
// R12: f16 packed-math gram (VALU 62 + MFMA 41 = 103% -> pure inst-count).
// R15: 64x64 gram tiles: gram2 145us (issue-bound at 94%).
// R16: k_prep (MFMA norms + f16 convert): 363.6us total.
// R17: FAILED fusion experiment: k_gru with cross-XCD device-scope barriers
//   = 246us (MFMA 1.9%!). ~45us per AGENT-scope barrier round on MI355X
//   (per-XCD L2 non-coherence). REVERTED. Budget re-audit: R16's 219us of
//   non-gram2 time IS the kernel work (k_step ~6us each, latency-bound) --
//   no launch-gap pool. So: remove work.
// R18 (this round): truncated scan (t >= T0=7 only): gram2/prep/scanlast
//   compute 9/16 of the timesteps. GRU path = R16 verbatim.

typedef __attribute__((ext_vector_type(8))) short bf16x8;
typedef __attribute__((ext_vector_type(4))) float f32x4;
typedef __attribute__((ext_vector_type(8))) _Float16 half8;
typedef __attribute__((ext_vector_type(2))) _Float16 h2;

__device__ __forceinline__ unsigned short f2bf(float f) {
    union { float f; unsigned u; } v; v.f = f;
    unsigned r = (v.u + 0x7FFF + ((v.u >> 16) & 1)) >> 16;
    return (unsigned short)r;
}
__device__ __forceinline__ float bf2f(unsigned short u) {
    union { unsigned u; float f; } v; v.u = ((unsigned)u) << 16; return v.f;
}
__device__ __forceinline__ unsigned pack2(unsigned short a, unsigned short b) {
    return (unsigned)a | ((unsigned)b << 16);
}
// packed f32->f16 convert (RTZ), 1 inst for 2 elems
__device__ __forceinline__ unsigned pkrtz(float a, float b) {
    unsigned r;
    asm("v_cvt_pkrtz_f16_f32 %0, %1, %2" : "=v"(r) : "v"(a), "v"(b));
    return r;
}
__device__ __forceinline__ h2 u2h(unsigned u) {
    union { unsigned u; h2 h; } v; v.u = u; return v.h;
}
__device__ __forceinline__ float sigmoidf_(float x) {
    return 1.0f / (1.0f + __expf(-x));
}
__device__ __forceinline__ float tanhf_(float x) {
    return 1.0f - 2.0f / (__expf(2.0f * x) + 1.0f);
}

// ---------------------------------------------------------------------------
// prep: per LIVE tb block (TBLIVE=288 blocks, tb = T0*32 + bid):
//   xh = f16(x), invnH via MFMA (A = x^2 f16 LDS XOR-swizzled, B = w^2 L1).
// ---------------------------------------------------------------------------
__global__ __launch_bounds__(256) void k_prep(const float* __restrict__ x,
                                              const unsigned* __restrict__ wsqH,
                                              unsigned short* __restrict__ xh,
                                              unsigned* __restrict__ invnH) {
    int tb = T0 * BB + blockIdx.x;
    int tid = threadIdx.x;
    int wave = tid >> 6, lane = tid & 63;
    int m16 = lane & 15, quad = lane >> 4;

    __shared__ unsigned short xsq[256 * 128];   // 64 KB f16, XOR-16 by row&7

    const float* xb = x + ((size_t)tb << 15);
    unsigned short* xhb = xh + ((size_t)tb << 15);

    #pragma unroll
    for (int it = 0; it < 16; ++it) {
        int flat = (it << 11) + (tid << 3);
        float4 a = *(const float4*)(xb + flat);
        float4 b = *(const float4*)(xb + flat + 4);
        uint4 o;
        o.x = pkrtz(a.x, a.y); o.y = pkrtz(a.z, a.w);
        o.z = pkrtz(b.x, b.y); o.w = pkrtz(b.z, b.w);
        *(uint4*)(xhb + flat) = o;
        uint4 q;
        q.x = pkrtz(a.x * a.x, a.y * a.y); q.y = pkrtz(a.z * a.z, a.w * a.w);
        q.z = pkrtz(b.x * b.x, b.y * b.y); q.w = pkrtz(b.z * b.z, b.w * b.w);
        int row = flat >> 7;
        int byteoff = (flat << 1) ^ ((row & 7) << 4);
        *(uint4*)((char*)xsq + byteoff) = q;
    }
    __syncthreads();

    half8 wf[4];
    #pragma unroll
    for (int ks = 0; ks < 4; ++ks)
        wf[ks] = *(const half8*)((const unsigned short*)wsqH + (m16 << 7) + (ks << 5) + (quad << 3));

    #pragma unroll
    for (int sub = 0; sub < 4; ++sub) {
        int rbase = (wave << 6) + (sub << 4);
        f32x4 acc = (f32x4){0.f, 0.f, 0.f, 0.f};
        #pragma unroll
        for (int ks = 0; ks < 4; ++ks) {
            int row = rbase + m16;
            int byteoff = ((row << 8) + (ks << 6) + (quad << 4)) ^ ((row & 7) << 4);
            half8 af = *(const half8*)((const char*)xsq + byteoff);
            acc = __builtin_amdgcn_mfma_f32_16x16x32_f16(af, wf[ks], acc, 0, 0, 0);
        }
        unsigned out[4];
        #pragma unroll
        for (int r = 0; r < 4; ++r) {
            float inv = 1.0f / (sqrtf(acc[r]) + EPSF);
            out[r] = pkrtz(inv, inv);
        }
        int n = rbase + (quad << 2);
        *(uint4*)(invnH + ((size_t)tb << 12) + (m16 << 8) + n) = *(uint4*)out;
    }
}

// ---------------------------------------------------------------------------
// gram2 (f16 packed, 64x64 wave tiles) — VERIFIED R15/R16; live-t grid only.
// grid = 4 rg x 288 tb = 1152 blocks, 256 threads, LDS 21 KB.
// ---------------------------------------------------------------------------
__global__ __launch_bounds__(256, 2) void k_gram2(const unsigned short* __restrict__ xhp,
                                                  const unsigned* __restrict__ wsqH,
                                                  const unsigned* __restrict__ invnH,
                                                  unsigned short* __restrict__ attn) {
    int bid = blockIdx.x;
    int rg = bid / TBLIVE;              // 0..3
    int tb = T0 * BB + (bid - rg * TBLIVE);
    int n0 = rg << 6;
    int tid = threadIdx.x;
    int wave = tid >> 6, lane = tid & 63;
    int m16 = lane & 15, quad = lane >> 4;
    int wcol = wave << 6;

    __shared__ unsigned wS[16 * 64];     // 4 KB
    __shared__ unsigned ivS[16 * 256];   // 16 KB
    __shared__ float rsum[4][64];        // 1 KB

    const unsigned short* Xb = xhp + ((size_t)tb << 15);

    {
        uint4 v = *(const uint4*)(wsqH + (tid << 2));
        *(uint4*)(wS + (tid << 2)) = v;
    }
    {
        const unsigned* src = invnH + ((size_t)tb << 12);
        #pragma unroll
        for (int hh = 0; hh < 16; ++hh)
            ivS[(hh << 8) + tid] = src[(hh << 8) + tid];
    }

    half8 Bf[4][4];
    #pragma unroll
    for (int ks = 0; ks < 4; ++ks)
        #pragma unroll
        for (int cb = 0; cb < 4; ++cb)
            Bf[ks][cb] = *(const half8*)(Xb + ((wcol + (cb << 4) + m16) << 7) + (ks << 5) + (quad << 3));

    half8 Af[4][4];
    #pragma unroll
    for (int rb = 0; rb < 4; ++rb)
        #pragma unroll
        for (int ks = 0; ks < 4; ++ks)
            Af[rb][ks] = *(const half8*)(Xb + ((n0 + (rb << 4) + m16) << 7) + (ks << 5) + (quad << 3));

    f32x4 att[4][4];
    #pragma unroll
    for (int rb = 0; rb < 4; ++rb)
        #pragma unroll
        for (int cb = 0; cb < 4; ++cb) att[rb][cb] = (f32x4){0.f, 0.f, 0.f, 0.f};

    __syncthreads();

    union H8 { half8 v; h2 p[4]; };

    #pragma unroll 1
    for (int h = 0; h < 16; ++h) {
        const unsigned* ivh = ivS + (h << 8);
        h2 ivr[4], ivc[4];
        #pragma unroll
        for (int rb = 0; rb < 4; ++rb) ivr[rb] = u2h(ivh[n0 + (rb << 4) + m16]);
        #pragma unroll
        for (int cb = 0; cb < 4; ++cb) ivc[cb] = u2h(ivh[wcol + (cb << 4) + m16]);

        #pragma unroll
        for (int ks = 0; ks < 4; ++ks) {
            uint4 wu = *(const uint4*)(wS + (h << 6) + (ks << 4) + (quad << 2));
            h2 w0 = u2h(wu.x), w1 = u2h(wu.y), w2 = u2h(wu.z), w3 = u2h(wu.w);

            H8 afr[4];
            #pragma unroll
            for (int rb = 0; rb < 4; ++rb) {
                H8 a; a.v = Af[rb][ks];
                h2 s = ivr[rb];
                afr[rb].p[0] = a.p[0] * (w0 * s);
                afr[rb].p[1] = a.p[1] * (w1 * s);
                afr[rb].p[2] = a.p[2] * (w2 * s);
                afr[rb].p[3] = a.p[3] * (w3 * s);
            }
            #pragma unroll
            for (int cb = 0; cb < 4; ++cb) {
                H8 b; b.v = Bf[ks][cb];
                H8 bf;
                bf.p[0] = b.p[0] * ivc[cb];
                bf.p[1] = b.p[1] * ivc[cb];
                bf.p[2] = b.p[2] * ivc[cb];
                bf.p[3] = b.p[3] * ivc[cb];
                #pragma unroll
                for (int rb = 0; rb < 4; ++rb)
                    att[rb][cb] = __builtin_amdgcn_mfma_f32_16x16x32_f16(afr[rb].v, bf.v, att[rb][cb], 0, 0, 0);
            }
        }
    }

    float rs[4][4];
    #pragma unroll
    for (int rb = 0; rb < 4; ++rb)
        #pragma unroll
        for (int r = 0; r < 4; ++r) {
            float s = 0.f;
            #pragma unroll
            for (int cb = 0; cb < 4; ++cb) {
                float v = fmaxf(att[rb][cb][r], 0.0f);
                att[rb][cb][r] = v;
                s += v;
            }
            rs[rb][r] = s;
        }
    #pragma unroll
    for (int m = 1; m < 16; m <<= 1)
        #pragma unroll
        for (int rb = 0; rb < 4; ++rb)
            #pragma unroll
            for (int r = 0; r < 4; ++r)
                rs[rb][r] += __shfl_xor(rs[rb][r], m, 64);
    if (m16 == 0) {
        #pragma unroll
        for (int rb = 0; rb < 4; ++rb)
            #pragma unroll
            for (int r = 0; r < 4; ++r)
                rsum[wave][(rb << 4) + (quad << 2) + r] = rs[rb][r];
    }
    __syncthreads();

    unsigned short* outb = attn + ((size_t)tb << 16);
    #pragma unroll
    for (int rb = 0; rb < 4; ++rb) {
        #pragma unroll
        for (int r = 0; r < 4; ++r) {
            int row = (rb << 4) + (quad << 2) + r;
            float tot = rsum[0][row] + rsum[1][row] + rsum[2][row] + rsum[3][row];
            float inv = (1.0f - SKIPF) / (tot + 16.0f * EPSF);
            #pragma unroll
            for (int cb = 0; cb < 4; ++cb) {
                int col = wcol + (cb << 4) + m16;
                outb[((size_t)(n0 + row) << 8) + col] = f2bf(att[rb][cb][r] * inv);
            }
        }
    }
}

// ---------------------------------------------------------------------------
// scanlast: a = supports*0.3^T0 (folded dead steps); a = 0.3a + attn_t for
// t = T0..15; write A_15 (bf16). grid 2048x256.
// ---------------------------------------------------------------------------
__global__ __launch_bounds__(256) void k_scanlast(const float* __restrict__ supports,
                                                  const unsigned short* __restrict__ AttA,
                                                  unsigned short* __restrict__ Afin) {
    size_t flat = ((size_t)blockIdx.x * 256 + threadIdx.x) * 4;
    float4 s4 = *(const float4*)(supports + flat);
    const float s7 = SKIPF * SKIPF * SKIPF * SKIPF * SKIPF * SKIPF * SKIPF; // 0.3^T0
    float a0 = s4.x * s7, a1 = s4.y * s7, a2 = s4.z * s7, a3 = s4.w * s7;
    #pragma unroll
    for (int t = T0; t < TT; ++t) {
        const unsigned short* p = AttA + ((size_t)t << 21) + flat;
        uint2 u = *(const uint2*)p;
        a0 = SKIPF * a0 + bf2f((unsigned short)(u.x & 0xffff));
        a1 = SKIPF * a1 + bf2f((unsigned short)(u.x >> 16));
        a2 = SKIPF * a2 + bf2f((unsigned short)(u.y & 0xffff));
        a3 = SKIPF * a3 + bf2f((unsigned short)(u.y >> 16));
    }
    uint2 o;
    o.x = pack2(f2bf(a0), f2bf(a1));
    o.y = pack2(f2bf(a2), f2bf(a3));
    *(uint2*)(Afin + flat) = o;
}

// ---------------------------------------------------------------------------
// hTinit: hT0[b][d][n] = bf16(x15[b][n][d]) for b=0..31. grid 32*32 blocks.
// ---------------------------------------------------------------------------
__global__ __launch_bounds__(256) void k_hTinit(const float* __restrict__ x15,
                                                unsigned short* __restrict__ hT) {
    int bid = blockIdx.x;
    int b = bid >> 5; int r = bid & 31; int d0 = (r >> 3) << 5; int n0 = (r & 7) << 5;
    __shared__ float tl[32][33];
    int tid = threadIdx.x;
    int i = tid >> 5, j = tid & 31;
    #pragma unroll
    for (int s = 0; s < 4; ++s) {
        int nl = (s << 3) + i;
        tl[nl][j] = x15[((size_t)(b * 256 + n0 + nl) << 7) + d0 + j];
    }
    __syncthreads();
    #pragma unroll
    for (int s = 0; s < 4; ++s) {
        int dd = (s << 3) + i;
        hT[((size_t)(b * 128 + d0 + dd) << 8) + n0 + j] = f2bf(tl[j][dd]);
    }
}

// ---------------------------------------------------------------------------
// wprep: bf16-transposed weights WT[dout][k] + packed-f16 w^2 table
// ---------------------------------------------------------------------------
__global__ __launch_bounds__(256) void k_wprep(const float* __restrict__ Wa,
                                               const float* __restrict__ Wr,
                                               const float* __restrict__ Wz,
                                               const float* __restrict__ Wh,
                                               const float* __restrict__ Wgl,
                                               unsigned short* __restrict__ WaT,
                                               unsigned short* __restrict__ WrT,
                                               unsigned short* __restrict__ WzT,
                                               unsigned short* __restrict__ WhT,
                                               unsigned* __restrict__ wsqH) {
    int idx = blockIdx.x * 256 + threadIdx.x;     // 0..32767
    if (idx < 16384) {
        int dout = idx >> 7, din = idx & 127;
        WaT[idx] = f2bf(Wa[(din << 7) + dout]);
    }
    if (idx < 1024) {
        int h = idx >> 6, j = idx & 63;
        float w0 = Wgl[(h << 7) + (j << 1)];
        float w1 = Wgl[(h << 7) + (j << 1) + 1];
        wsqH[idx] = pkrtz(w0 * w0, w1 * w1);
    }
    {
        int dout = idx >> 8, dk = idx & 255;
        WrT[idx] = f2bf(Wr[(dk << 7) + dout]);
        WzT[idx] = f2bf(Wz[(dk << 7) + dout]);
        WhT[idx] = f2bf(Wh[(dk << 7) + dout]);
    }
}

// ---------------------------------------------------------------------------
// step: fused GGNN/GRU step for t=15 only — VERIFIED R16 version.
// grid = 8 rg x 32 b = 256 blocks.
// ---------------------------------------------------------------------------
__global__ __launch_bounds__(256) void k_step(
    const unsigned short* __restrict__ Afin,
    const unsigned short* __restrict__ hT,
    const unsigned short* __restrict__ WaT, const float* __restrict__ ba,
    const unsigned short* __restrict__ WrT, const float* __restrict__ br,
    const unsigned short* __restrict__ WzT, const float* __restrict__ bz,
    const unsigned short* __restrict__ WhT, const float* __restrict__ bh,
    unsigned short* __restrict__ hT_o) {

    int bid = blockIdx.x;
    int b = bid & 31, rg = bid >> 5;
    int n0 = rg << 5;
    int tid = threadIdx.x;
    int wave = tid >> 6, lane = tid & 63;
    int m16 = lane & 15, quad = lane >> 4;
    int wcol = wave << 5;

    __shared__ unsigned short msgS[32 * 136];
    __shared__ unsigned short ahS[32 * 264];   // k 0..127 = a, 128..255 = h (later r*h)

    const unsigned short* hTb = hT + ((size_t)b << 15);

    // stage h-half of ahS from hT (transpose: ahS[row][128+d] = hT[d][n0+row])
    #pragma unroll
    for (int j = 0; j < 16; ++j) {
        int idx = (j << 8) + tid;            // 0..4095
        int d = idx >> 5, row = idx & 31;
        ahS[row * 264 + 128 + d] = hTb[((size_t)d << 8) + n0 + row];
    }

    // ---- bmm: msg = A_tile @ h  (K=256) ----
    f32x4 acc[2][2];
    #pragma unroll
    for (int rb = 0; rb < 2; ++rb)
        #pragma unroll
        for (int cb = 0; cb < 2; ++cb) acc[rb][cb] = (f32x4){0.f, 0.f, 0.f, 0.f};

    const unsigned short* Ab = Afin + ((size_t)b << 16) + ((size_t)n0 << 8);
    #pragma unroll 2
    for (int ks = 0; ks < 8; ++ks) {
        bf16x8 af[2], bf[2];
        #pragma unroll
        for (int rb = 0; rb < 2; ++rb)
            af[rb] = *(const bf16x8*)(Ab + (((rb << 4) + m16) << 8) + (ks << 5) + (quad << 3));
        #pragma unroll
        for (int cb = 0; cb < 2; ++cb)
            bf[cb] = *(const bf16x8*)(hTb + ((wcol + (cb << 4) + m16) << 8) + (ks << 5) + (quad << 3));
        #pragma unroll
        for (int rb = 0; rb < 2; ++rb)
            #pragma unroll
            for (int cb = 0; cb < 2; ++cb)
                acc[rb][cb] = __builtin_amdgcn_mfma_f32_16x16x32_bf16(af[rb], bf[cb], acc[rb][cb], 0, 0, 0);
    }
    #pragma unroll
    for (int rb = 0; rb < 2; ++rb)
        #pragma unroll
        for (int cb = 0; cb < 2; ++cb)
            #pragma unroll
            for (int r = 0; r < 4; ++r)
                msgS[((rb << 4) + (quad << 2) + r) * 136 + wcol + (cb << 4) + m16] = f2bf(acc[rb][cb][r]);
    __syncthreads();   // covers h-half staging too

    // ---- a = msg @ Wa + ba ----
    #pragma unroll
    for (int rb = 0; rb < 2; ++rb)
        #pragma unroll
        for (int cb = 0; cb < 2; ++cb) acc[rb][cb] = (f32x4){0.f, 0.f, 0.f, 0.f};
    #pragma unroll
    for (int ks = 0; ks < 4; ++ks) {
        bf16x8 af[2], bf[2];
        #pragma unroll
        for (int rb = 0; rb < 2; ++rb)
            af[rb] = *(const bf16x8*)(msgS + ((rb << 4) + m16) * 136 + (ks << 5) + (quad << 3));
        #pragma unroll
        for (int cb = 0; cb < 2; ++cb)
            bf[cb] = *(const bf16x8*)(WaT + ((wcol + (cb << 4) + m16) << 7) + (ks << 5) + (quad << 3));
        #pragma unroll
        for (int rb = 0; rb < 2; ++rb)
            #pragma unroll
            for (int cb = 0; cb < 2; ++cb)
                acc[rb][cb] = __builtin_amdgcn_mfma_f32_16x16x32_bf16(af[rb], bf[cb], acc[rb][cb], 0, 0, 0);
    }
    {
        float bav[2];
        #pragma unroll
        for (int cb = 0; cb < 2; ++cb) bav[cb] = ba[wcol + (cb << 4) + m16];
        #pragma unroll
        for (int rb = 0; rb < 2; ++rb)
            #pragma unroll
            for (int cb = 0; cb < 2; ++cb)
                #pragma unroll
                for (int r = 0; r < 4; ++r)
                    ahS[((rb << 4) + (quad << 2) + r) * 264 + wcol + (cb << 4) + m16] =
                        f2bf(acc[rb][cb][r] + bav[cb]);
    }
    __syncthreads();

    // h_old (for r*h and final update): uint2 = 4 consecutive n at fixed col
    float hv[2][2][4];
    #pragma unroll
    for (int rb = 0; rb < 2; ++rb)
        #pragma unroll
        for (int cb = 0; cb < 2; ++cb) {
            int col = wcol + (cb << 4) + m16;
            uint2 u = *(const uint2*)(hTb + ((size_t)col << 8) + n0 + (rb << 4) + (quad << 2));
            hv[rb][cb][0] = bf2f((unsigned short)(u.x & 0xffff));
            hv[rb][cb][1] = bf2f((unsigned short)(u.x >> 16));
            hv[rb][cb][2] = bf2f((unsigned short)(u.y & 0xffff));
            hv[rb][cb][3] = bf2f((unsigned short)(u.y >> 16));
        }

    // ---- r and z ----
    f32x4 racc[2][2], zacc[2][2];
    #pragma unroll
    for (int rb = 0; rb < 2; ++rb)
        #pragma unroll
        for (int cb = 0; cb < 2; ++cb) {
            racc[rb][cb] = (f32x4){0.f, 0.f, 0.f, 0.f};
            zacc[rb][cb] = (f32x4){0.f, 0.f, 0.f, 0.f};
        }
    #pragma unroll 2
    for (int ks = 0; ks < 8; ++ks) {
        bf16x8 af[2], bfr[2], bfz[2];
        #pragma unroll
        for (int rb = 0; rb < 2; ++rb)
            af[rb] = *(const bf16x8*)(ahS + ((rb << 4) + m16) * 264 + (ks << 5) + (quad << 3));
        #pragma unroll
        for (int cb = 0; cb < 2; ++cb) {
            int dout = wcol + (cb << 4) + m16;
            bfr[cb] = *(const bf16x8*)(WrT + (dout << 8) + (ks << 5) + (quad << 3));
            bfz[cb] = *(const bf16x8*)(WzT + (dout << 8) + (ks << 5) + (quad << 3));
        }
        #pragma unroll
        for (int rb = 0; rb < 2; ++rb)
            #pragma unroll
            for (int cb = 0; cb < 2; ++cb) {
                racc[rb][cb] = __builtin_amdgcn_mfma_f32_16x16x32_bf16(af[rb], bfr[cb], racc[rb][cb], 0, 0, 0);
                zacc[rb][cb] = __builtin_amdgcn_mfma_f32_16x16x32_bf16(af[rb], bfz[cb], zacc[rb][cb], 0, 0, 0);
            }
    }
    float zv[2][2][4];
    {
        float brv[2], bzv[2];
        #pragma unroll
        for (int cb = 0; cb < 2; ++cb) {
            brv[cb] = br[wcol + (cb << 4) + m16];
            bzv[cb] = bz[wcol + (cb << 4) + m16];
        }
        #pragma unroll
        for (int rb = 0; rb < 2; ++rb)
            #pragma unroll
            for (int cb = 0; cb < 2; ++cb)
                #pragma unroll
                for (int r = 0; r < 4; ++r) {
                    racc[rb][cb][r] = sigmoidf_(racc[rb][cb][r] + brv[cb]);
                    zv[rb][cb][r]  = sigmoidf_(zacc[rb][cb][r] + bzv[cb]);
                }
    }
    __syncthreads();   // all ahS reads done -> safe to overwrite h-half

    #pragma unroll
    for (int rb = 0; rb < 2; ++rb)
        #pragma unroll
        for (int cb = 0; cb < 2; ++cb)
            #pragma unroll
            for (int r = 0; r < 4; ++r)
                ahS[((rb << 4) + (quad << 2) + r) * 264 + 128 + wcol + (cb << 4) + m16] =
                    f2bf(racc[rb][cb][r] * hv[rb][cb][r]);
    __syncthreads();

    // ---- h_tilde ----
    #pragma unroll
    for (int rb = 0; rb < 2; ++rb)
        #pragma unroll
        for (int cb = 0; cb < 2; ++cb) acc[rb][cb] = (f32x4){0.f, 0.f, 0.f, 0.f};
    #pragma unroll 2
    for (int ks = 0; ks < 8; ++ks) {
        bf16x8 af[2], bf[2];
        #pragma unroll
        for (int rb = 0; rb < 2; ++rb)
            af[rb] = *(const bf16x8*)(ahS + ((rb << 4) + m16) * 264 + (ks << 5) + (quad << 3));
        #pragma unroll
        for (int cb = 0; cb < 2; ++cb)
            bf[cb] = *(const bf16x8*)(WhT + ((wcol + (cb << 4) + m16) << 8) + (ks << 5) + (quad << 3));
        #pragma unroll
        for (int rb = 0; rb < 2; ++rb)
            #pragma unroll
            for (int cb = 0; cb < 2; ++cb)
                acc[rb][cb] = __builtin_amdgcn_mfma_f32_16x16x32_bf16(af[rb], bf[cb], acc[rb][cb], 0, 0, 0);
    }

    // ---- update + writes (hT only) ----
    {
        float bhv[2];
        #pragma unroll
        for (int cb = 0; cb < 2; ++cb) bhv[cb] = bh[wcol + (cb << 4) + m16];
        #pragma unroll
        for (int rb = 0; rb < 2; ++rb)
            #pragma unroll
            for (int cb = 0; cb < 2; ++cb) {
                int col = wcol + (cb << 4) + m16;
                unsigned short pk[4];
                #pragma unroll
                for (int r = 0; r < 4; ++r) {
                    float ht = tanhf_(acc[rb][cb][r] + bhv[cb]);
                    float hn = hv[rb][cb][r] + zv[rb][cb][r] * (ht - hv[rb][cb][r]);
                    pk[r] = f2bf(hn);
                }
                uint2 p;
                p.x = pack2(pk[0], pk[1]); p.y = pack2(pk[2], pk[3]);
                *(uint2*)(hT_o + ((size_t)(b * 128 + col) << 8) + n0 + (rb << 4) + (quad << 2)) = p;
            }
    }
}

// ---------------------------------------------------------------------------
// fc: logits[b,c] = sum over col-major h (hT1, b slice) + bfc. grid = 512.
// ---------------------------------------------------------------------------
__global__ __launch_bounds__(256) void k_fc(const unsigned short* __restrict__ hT,
                                            const float* __restrict__ Wfc,
                                            const float* __restrict__ bfc,
                                            float* __restrict__ out) {
    int bid = blockIdx.x;
    int b = bid >> 4, part = bid & 15;
    int tid = threadIdx.x;
    const unsigned short* hp = hT + ((size_t)b << 15);
    int i = part * 2048 + tid * 8;       // linear col-major: i = d*256 + n
    int d = i >> 8, n = i & 255;
    uint4 hu = *(const uint4*)(hp + i);
    unsigned short hs[8];
    hs[0] = hu.x & 0xffff; hs[1] = hu.x >> 16;
    hs[2] = hu.y & 0xffff; hs[3] = hu.y >> 16;
    hs[4] = hu.z & 0xffff; hs[5] = hu.z >> 16;
    hs[6] = hu.w & 0xffff; hs[7] = hu.w >> 16;
    float a0 = 0.f, a1 = 0.f;
    #pragma unroll
    for (int k = 0; k < 8; ++k) {
        float v = bf2f(hs[k]);
        const float2 w = *(const float2*)(Wfc + ((size_t)(n + k) * 128 + d) * 2);
        a0 = fmaf(v, w.x, a0);
        a1 = fmaf(v, w.y, a1);
    }
    int wave = tid >> 6, lane = tid & 63;
    #pragma unroll
    for (int off = 32; off; off >>= 1) {
        a0 += __shfl_down(a0, off, 64);
        a1 += __shfl_down(a1, off, 64);
    }
    __shared__ float r0[4], r1[4];
    if (lane == 0) { r0[wave] = a0; r1[wave] = a1; }
    __syncthreads();
    if (tid == 0) {
        float s0 = r0[0] + r0[1] + r0[2] + r0[3];
        float s1 = r1[0] + r1[1] + r1[2] + r1[3];
        if (part == 0) { s0 += bfc[0]; s1 += bfc[1]; }
        atomicAdd(&out[b * 2 + 0], s0);
        atomicAdd(&out[b * 2 + 1], s1);
    }
}

// ---------------------------------------------------------------------------
extern "C" void kernel_launch(void* const* d_in, const int* in_sizes, int n_in,
                              void* d_out, int out_size, void* d_ws, size_t ws_size,
                              hipStream_t stream) {
    const float* x_all    = (const float*)d_in[0];
    const float* supports = (const float*)d_in[1];
    const float* Wgl = (const float*)d_in[2];
    const float* Wa  = (const float*)d_in[3];
    const float* ba  = (const float*)d_in[4];
    const float* Wr  = (const float*)d_in[5];
    const float* br  = (const float*)d_in[6];
    const float* Wz  = (const float*)d_in[7];
    const float* bz  = (const float*)d_in[8];
    const float* Wh  = (const float*)d_in[9];
    const float* bh  = (const float*)d_in[10];
    const float* Wfc = (const float*)d_in[11];
    const float* bfc = (const float*)d_in[12];
    float* out = (float*)d_out;

    char* p = (char*)d_ws;
    auto alloc = [&](size_t bytes) { char* r = p; p += (bytes + 255) & ~(size_t)255; return r; };

    unsigned short* AttA = (unsigned short*)alloc((size_t)TT * BB * NN * NN * 2);  // 64 MB
    unsigned short* xh   = (unsigned short*)alloc((size_t)TT * BB * NN * DD * 2);  // 32 MB (f16)
    unsigned* invnH      = (unsigned*)alloc((size_t)TT * BB * 16 * NN * 4);        // 8 MB (dup f16)
    unsigned short* Afin = (unsigned short*)alloc((size_t)BB * NN * NN * 2);       // 4 MB
    unsigned short* hT0  = (unsigned short*)alloc((size_t)BB * DD * NN * 2);       // 2 MB
    unsigned short* hT1  = (unsigned short*)alloc((size_t)BB * DD * NN * 2);       // 2 MB
    unsigned short* WaT  = (unsigned short*)alloc(128 * 128 * 2);
    unsigned short* WrT  = (unsigned short*)alloc(256 * 128 * 2);
    unsigned short* WzT  = (unsigned short*)alloc(256 * 128 * 2);
    unsigned short* WhT  = (unsigned short*)alloc(256 * 128 * 2);
    unsigned* wsqH       = (unsigned*)alloc(16 * 64 * 4);                          // 4 KB
    // total ~112.5 MB

    k_wprep<<<128, 256, 0, stream>>>(Wa, Wr, Wz, Wh, Wgl, WaT, WrT, WzT, WhT, wsqH);
    k_prep<<<TBLIVE, 256, 0, stream>>>(x_all, wsqH, xh, invnH);

    // attention path: live timesteps (t >= T0) in one dispatch
    k_gram2<<<4 * TBLIVE, 256, 0, stream>>>(xh, wsqH, invnH, AttA);
    k_scanlast<<<2048, 256, 0, stream>>>(supports, AttA, Afin);

    // GRU path: ONLY t=15 is live (reference uses outs[-1] only)
    const float* x15 = x_all + (size_t)15 * BB * NN * DD;
    k_hTinit<<<BB * 32, 256, 0, stream>>>(x15, hT0);

    const unsigned short* hT_in = hT0;
    for (int s = 0; s < NSTEPS; ++s) {
        unsigned short* hTo = (s & 1) ? hT0 : hT1;
        k_step<<<8 * BB, 256, 0, stream>>>(Afin, hT_in,
                                           WaT, ba, WrT, br, WzT, bz, WhT, bh,
                                           hTo);
        hT_in = hTo;
    }
    // after 5 steps (s=4) final h is in hT1
    hipMemsetAsync(d_out, 0, (size_t)out_size * sizeof(float), stream);
    k_fc<<<BB * 16, 256, 0, stream>>>(hT1, Wfc, bfc, out);
}